// Round 8
// baseline (218.415 us; speedup 1.0000x reference)
//
#include <hip/hip_runtime.h>
#include <hip/hip_bf16.h>
#include <stdint.h>

typedef __bf16 bf16;
typedef __bf16 bf16x8 __attribute__((ext_vector_type(8)));
typedef float f32x4 __attribute__((ext_vector_type(4)));
typedef float f32x16 __attribute__((ext_vector_type(16)));

#define BATCH 4
#define SEQ   2048
#define DIM   1024
#define NH    16
#define HD    64

// Q projection pre-scaled by (1/sqrt(HD)) * log2(e): softmax runs in exp2 domain.
#define QSCALE 0.18033688011112042f  // 0.125 * 1.4426950408889634

#define MFMA(a, b, c)   __builtin_amdgcn_mfma_f32_16x16x32_bf16((a), (b), (c), 0, 0, 0)
#define MFMA32(a, b, c) __builtin_amdgcn_mfma_f32_32x32x16_bf16((a), (b), (c), 0, 0, 0)

// global -> LDS direct copy, 16B per lane. LDS dest is wave-uniform base+lane*16.
#define GLOAD16(gsrc, ldst)                                                        \
  __builtin_amdgcn_global_load_lds(                                                \
      (__attribute__((address_space(1))) unsigned int*)(void*)(gsrc),              \
      (__attribute__((address_space(3))) unsigned int*)(ldst), 16, 0, 0)

static __device__ __forceinline__ float fast_exp2(float x) {
#if __has_builtin(__builtin_amdgcn_exp2f)
  return __builtin_amdgcn_exp2f(x);
#else
  return exp2f(x);
#endif
}

// ---------------------------------------------------------------------------
// Weight conversion: f32 -> bf16, 4 tensors of DIM*DIM each.
// ---------------------------------------------------------------------------
__global__ __launch_bounds__(256) void cvt_w_kernel(
    const float* __restrict__ w0, const float* __restrict__ w1,
    const float* __restrict__ w2, const float* __restrict__ w3,
    bf16* __restrict__ o0, bf16* __restrict__ o1,
    bf16* __restrict__ o2, bf16* __restrict__ o3) {
  const float* s;
  bf16* d;
  switch (blockIdx.y) {
    case 0: s = w0; d = o0; break;
    case 1: s = w1; d = o1; break;
    case 2: s = w2; d = o2; break;
    default: s = w3; d = o3; break;
  }
  const int i = (blockIdx.x * 256 + threadIdx.x) * 4;
  const float4 v = *(const float4*)(s + i);
  ushort4 o;
  o.x = __builtin_bit_cast(unsigned short, (bf16)v.x);
  o.y = __builtin_bit_cast(unsigned short, (bf16)v.y);
  o.z = __builtin_bit_cast(unsigned short, (bf16)v.z);
  o.w = __builtin_bit_cast(unsigned short, (bf16)v.w);
  *(ushort4*)((unsigned short*)d + i) = o;
}

// ---------------------------------------------------------------------------
// Activation conversion: f32 -> bf16, BATCH*SEQ*DIM elements, 8/thread.
// ---------------------------------------------------------------------------
__global__ __launch_bounds__(256) void cvt_x_kernel(
    const float* __restrict__ in, bf16* __restrict__ out) {
  const int i = (blockIdx.x * 256 + threadIdx.x) * 8;
  const float4 v0 = *(const float4*)(in + i);
  const float4 v1 = *(const float4*)(in + i + 4);
  bf16x8 p;
  p[0] = (bf16)v0.x; p[1] = (bf16)v0.y; p[2] = (bf16)v0.z; p[3] = (bf16)v0.w;
  p[4] = (bf16)v1.x; p[5] = (bf16)v1.y; p[6] = (bf16)v1.z; p[7] = (bf16)v1.w;
  *(bf16x8*)(out + i) = p;
}

// ---------------------------------------------------------------------------
// Projection GEMM (pure bf16, R6 known-good form): C = A·W^T + bias.
// BK=64, double-buffered, __syncthreads pipeline, 128B rows with (row&7)<<4
// XOR swizzle (0 conflicts), XCD-chunked block swizzle.
// z=0: out = bf16(C * QSCALE) (Q) | z=1: bf16(C) (K) | z=2: Vt transposed.
// ---------------------------------------------------------------------------
__global__ __launch_bounds__(256, 2) void proj_gemm(
    const bf16* __restrict__ A, const bf16* __restrict__ W,
    const float* __restrict__ bias, bf16* __restrict__ out, int z) {
  __shared__ bf16 Ab[2][128 * 64];
  __shared__ bf16 Bb[2][128 * 64];

  const int tid  = threadIdx.x;
  const int wave = tid >> 6, lane = tid & 63;
  const int r = lane & 15, g = lane >> 4;

  const int wg = blockIdx.x;
  const int sw = ((wg & 7) << 6) | (wg >> 3);
  const int m0 = (sw >> 3) * 128, n0 = (sw & 7) * 128;
  const int wm = (wave >> 1) * 64, wn = (wave & 1) * 64;

  f32x4 acc[4][4] = {};

  const int srr = lane >> 3;
  const int scb = (lane & 7) * 16;
  const int swz = srr << 4;

#define STAGEP(buf, k0)                                                             \
  do {                                                                              \
    _Pragma("unroll") for (int i_ = 0; i_ < 4; ++i_) {                              \
      const int row_ = wave * 32 + i_ * 8 + srr;                                    \
      const char* as_ =                                                             \
          (const char*)(A + (size_t)(m0 + row_) * DIM + (k0)) + (scb ^ swz);        \
      GLOAD16(as_, (char*)&Ab[buf][0] + (wave * 32 + i_ * 8) * 128);                \
      const char* bs_ =                                                             \
          (const char*)(W + (size_t)(n0 + row_) * DIM + (k0)) + (scb ^ swz);        \
      GLOAD16(bs_, (char*)&Bb[buf][0] + (wave * 32 + i_ * 8) * 128);                \
    }                                                                               \
  } while (0)

  STAGEP(0, 0);
  __syncthreads();

  const int NK = DIM / 64;
  for (int it = 0; it < NK; ++it) {
    const int cur = it & 1;
    if (it + 1 < NK) STAGEP(cur ^ 1, (it + 1) * 64);

#pragma unroll
    for (int ks = 0; ks < 2; ++ks) {
      bf16x8 af[4], bfr[4];
#pragma unroll
      for (int mt = 0; mt < 4; ++mt) {
        const int mr = wm + mt * 16 + r;
        af[mt] = *(bf16x8*)((char*)&Ab[cur][0] + mr * 128 +
                            ((ks * 64 + g * 16) ^ ((mr & 7) << 4)));
      }
#pragma unroll
      for (int nt = 0; nt < 4; ++nt) {
        const int nr = wn + nt * 16 + r;
        bfr[nt] = *(bf16x8*)((char*)&Bb[cur][0] + nr * 128 +
                             ((ks * 64 + g * 16) ^ ((nr & 7) << 4)));
      }
#pragma unroll
      for (int mt = 0; mt < 4; ++mt)
#pragma unroll
        for (int nt = 0; nt < 4; ++nt)
          acc[mt][nt] = MFMA(af[mt], bfr[nt], acc[mt][nt]);
    }

    __syncthreads();
  }
#undef STAGEP

  // --- epilogue ---  C/D layout: row = g*4 + i, col = r (per 16x16 tile)
  if (z == 2) {
#pragma unroll
    for (int nt = 0; nt < 4; ++nt) {
      const int n = n0 + wn + nt * 16 + r;
      const float bn = bias[n];
#pragma unroll
      for (int mt = 0; mt < 4; ++mt) {
        const int m = m0 + wm + mt * 16 + g * 4;
        const int b = m >> 11, t = m & 2047;
        ushort4 pk;
        pk.x = __builtin_bit_cast(unsigned short, (bf16)(acc[mt][nt][0] + bn));
        pk.y = __builtin_bit_cast(unsigned short, (bf16)(acc[mt][nt][1] + bn));
        pk.z = __builtin_bit_cast(unsigned short, (bf16)(acc[mt][nt][2] + bn));
        pk.w = __builtin_bit_cast(unsigned short, (bf16)(acc[mt][nt][3] + bn));
        *(ushort4*)((unsigned short*)out + (((size_t)(b * DIM + n)) << 11) + t) = pk;
      }
    }
  } else {
    const float scale = (z == 0) ? QSCALE : 1.0f;
#pragma unroll
    for (int mt = 0; mt < 4; ++mt)
#pragma unroll
      for (int nt = 0; nt < 4; ++nt) {
        const int n = n0 + wn + nt * 16 + r;
        const float bn = bias[n];
#pragma unroll
        for (int i = 0; i < 4; ++i) {
          const int m = m0 + wm + mt * 16 + g * 4 + i;
          out[(size_t)m * DIM + n] = (bf16)((acc[mt][nt][i] + bn) * scale);
        }
      }
  }
}

// ---------------------------------------------------------------------------
// Fused attention, 32x32 swapped structure, FRAGMENT-LINEAR LDS:
// K and V staged as 1KB MFMA-fragment arrays (lane l's 16B at base+l*16),
// written natively by global_load_lds; per-lane GLOBAL source addresses carry
// the pi-permutation and fragment gather. Reads are base+lane*16+imm ->
// zero bank conflicts, zero swizzle VALU.
// Pipeline: K depth-2 (3 buffers), V depth-1 (2 buffers), counted vmcnt:
// steady vmcnt(6), tail 4/0. LDS 40KB -> 4 blocks/CU.
// ---------------------------------------------------------------------------
__global__ __launch_bounds__(256, 4) void attn_kernel(
    const bf16* __restrict__ Q, const bf16* __restrict__ K,
    const bf16* __restrict__ Vt, bf16* __restrict__ ctx) {
  // K: 3 buffers x 8 arrays (ka = kvt*4+st) x 1KB
  // V: 2 buffers x 8 arrays (va = dt*4+kvt*2+kb) x 1KB
  __shared__ alignas(16) char Kl[3 * 8192];
  __shared__ alignas(16) char Vl[2 * 8192];

  const int tid  = threadIdx.x;
  const int wave = tid >> 6, lane = tid & 63;
  const int l31 = lane & 31, hi = lane >> 5;

  // XCD-chunked swizzle: 8 heads (x16 q-blocks) per XCD
  const int wg  = blockIdx.x;
  const int swb = (wg & 7) * 128 + (wg >> 3);
  const int qblk = swb & 15, bh = swb >> 4;
  const int b = bh >> 4, h = bh & 15;
  const int q0 = qblk * 128 + wave * 32;

  // Q fragments (B operand): col q = lane&31, k(d) = st*16 + hi*8 + j
  bf16x8 qf[4];
  {
    const bf16* qp = Q + ((size_t)(b * SEQ + q0 + l31) * DIM + h * HD);
#pragma unroll
    for (int st = 0; st < 4; ++st)
      qf[st] = *(const bf16x8*)(qp + st * 16 + hi * 8);
  }

  f32x16 accO[2] = {};
  float m_i = -3e38f, l_i = 0.0f;

  const char* Kbase = (const char*)(K + (size_t)(b * SEQ) * DIM + h * HD);
  const char* Vbase = (const char*)(Vt + (size_t)(b * DIM + h * HD) * SEQ);

  // pi: swap bits 2,3 of the kv row (S^T C-layout -> PV B-operand order)
  const int t_ = (l31 >> 2) & 3;
  const int pl = (t_ == 1 || t_ == 2) ? (l31 ^ 12) : l31;

  // Per-wave staging: wave w owns K arrays {2w,2w+1} and V arrays {2w,2w+1}.
  int ksrc[2], kdst[2], vsrc[2], vdst[2];
#pragma unroll
  for (int i = 0; i < 2; ++i) {
    const int ka = wave * 2 + i;             // 0..7
    const int kvt = ka >> 2, st = ka & 3;
    ksrc[i] = ((kvt * 32 + pl) * DIM + st * 16 + hi * 8) * 2;
    kdst[i] = ka * 1024;
    const int va = wave * 2 + i;
    const int dt = va >> 2, kvt2 = (va >> 1) & 1, kb = va & 1;
    vsrc[i] = ((dt * 32 + l31) * SEQ + kvt2 * 32 + kb * 16 + hi * 8) * 2;
    vdst[i] = va * 1024;
  }

#define STAGE_K(kbuf, kv0)                                                          \
  do {                                                                              \
    _Pragma("unroll") for (int i_ = 0; i_ < 2; ++i_)                                \
        GLOAD16(Kbase + (size_t)(kv0) * (2 * DIM) + ksrc[i_],                       \
                Kl + (kbuf) * 8192 + kdst[i_]);                                     \
  } while (0)
#define STAGE_V(vbuf, kv0)                                                          \
  do {                                                                              \
    _Pragma("unroll") for (int i_ = 0; i_ < 2; ++i_)                                \
        GLOAD16(Vbase + (size_t)(kv0) * 2 + vsrc[i_],                               \
                Vl + (vbuf) * 8192 + vdst[i_]);                                     \
  } while (0)

  // prologue: K depth-2, V depth-1  (6 loads in flight per wave)
  STAGE_K(0, 0);
  STAGE_V(0, 0);
  STAGE_K(1, 64);

  int kc = 0;   // K buffer holding tile `it`
  int kst = 2;  // K buffer to stage tile `it+2` into
  const int NIT = SEQ / 64;
  for (int it = 0; it < NIT; ++it) {
    const int vcur = it & 1;
    if (it + 2 < NIT) {
      STAGE_K(kst, (it + 2) * 64);
      STAGE_V(vcur ^ 1, (it + 1) * 64);
      asm volatile("s_waitcnt vmcnt(6)" ::: "memory");  // tiles it+1,it+2 stay out
    } else if (it + 1 < NIT) {
      STAGE_V(vcur ^ 1, (it + 1) * 64);
      asm volatile("s_waitcnt vmcnt(4)" ::: "memory");
    } else {
      asm volatile("s_waitcnt vmcnt(0)" ::: "memory");
    }
    __builtin_amdgcn_s_barrier();
    asm volatile("" ::: "memory");

    // --- S^T = K·Q : 2 kv-tiles x 4 k-steps, fragment-linear reads ---
    const char* kbp = Kl + kc * 8192 + lane * 16;
    f32x16 s[2] = {};
    __builtin_amdgcn_s_setprio(1);
#pragma unroll
    for (int kvt = 0; kvt < 2; ++kvt)
#pragma unroll
      for (int st = 0; st < 4; ++st) {
        const bf16x8 kf = *(const bf16x8*)(kbp + (kvt * 4 + st) * 1024);
        s[kvt] = MFMA32(kf, qf[st], s[kvt]);
      }
    __builtin_amdgcn_s_setprio(0);

    // --- tile max, tree (depth 5) ---
    float pm;
    {
      f32x16 m16;
#pragma unroll
      for (int e = 0; e < 16; ++e) m16[e] = fmaxf(s[0][e], s[1][e]);
      f32x4 m4;
#pragma unroll
      for (int e = 0; e < 4; ++e)
        m4[e] = fmaxf(fmaxf(m16[e], m16[e + 4]), fmaxf(m16[e + 8], m16[e + 12]));
      pm = fmaxf(fmaxf(m4[0], m4[1]), fmaxf(m4[2], m4[3]));
      pm = fmaxf(pm, __shfl_xor(pm, 32));
    }

    // --- defer-max: rescale only when running max grew by > 8 (log2) ---
    if (__any(pm > m_i + 8.0f)) {
      const float mn = fmaxf(m_i, pm);
      const float alpha = fast_exp2(m_i - mn);
      m_i = mn;
      l_i *= alpha;
#pragma unroll
      for (int dt = 0; dt < 2; ++dt)
#pragma unroll
        for (int e = 0; e < 16; ++e) accO[dt][e] *= alpha;
    }

    // --- P = exp2(S - m); row-sum as tree ---
#pragma unroll
    for (int kvt = 0; kvt < 2; ++kvt)
#pragma unroll
      for (int e = 0; e < 16; ++e) s[kvt][e] = fast_exp2(s[kvt][e] - m_i);
    {
      f32x16 t16;
#pragma unroll
      for (int e = 0; e < 16; ++e) t16[e] = s[0][e] + s[1][e];
      f32x4 t4;
#pragma unroll
      for (int e = 0; e < 4; ++e)
        t4[e] = (t16[e] + t16[e + 4]) + (t16[e + 8] + t16[e + 12]);
      float rs = (t4[0] + t4[1]) + (t4[2] + t4[3]);
      l_i += rs + __shfl_xor(rs, 32);
    }

    // --- pack P to bf16 frags (in-register, thanks to pi-permuted K) ---
    bf16x8 pa[2][2];
#pragma unroll
    for (int kvt = 0; kvt < 2; ++kvt)
#pragma unroll
      for (int kb = 0; kb < 2; ++kb)
#pragma unroll
        for (int j = 0; j < 8; ++j)
          pa[kvt][kb][j] = (bf16)s[kvt][kb * 8 + j];

    // --- O^T += V^T · P, fragment-linear reads ---
    const char* vbp = Vl + vcur * 8192 + lane * 16;
    __builtin_amdgcn_s_setprio(1);
#pragma unroll
    for (int dt = 0; dt < 2; ++dt)
#pragma unroll
      for (int kvt = 0; kvt < 2; ++kvt)
#pragma unroll
        for (int kb = 0; kb < 2; ++kb) {
          const bf16x8 vf =
              *(const bf16x8*)(vbp + (dt * 4 + kvt * 2 + kb) * 1024);
          accO[dt] = MFMA32(vf, pa[kvt][kb], accO[dt]);
        }
    __builtin_amdgcn_s_setprio(0);

    if (it + 1 < NIT) {
      asm volatile("" ::: "memory");
      __builtin_amdgcn_s_barrier();  // buffers free for next iter's staging
      asm volatile("" ::: "memory");
    }
    kc = (kc == 2) ? 0 : kc + 1;
    kst = (kst == 2) ? 0 : kst + 1;
  }
#undef STAGE_K
#undef STAGE_V

  // --- normalize and write ctx: lane owns q = q0+l31, d = dt*32+rr*8+4hi+c ---
  {
    const float inv = 1.0f / l_i;
    bf16* cp = ctx + (size_t)(b * SEQ + q0 + l31) * DIM + h * HD;
#pragma unroll
    for (int dt = 0; dt < 2; ++dt)
#pragma unroll
      for (int rr = 0; rr < 4; ++rr) {
        ushort4 pk;
        pk.x = __builtin_bit_cast(unsigned short, (bf16)(accO[dt][rr * 4 + 0] * inv));
        pk.y = __builtin_bit_cast(unsigned short, (bf16)(accO[dt][rr * 4 + 1] * inv));
        pk.z = __builtin_bit_cast(unsigned short, (bf16)(accO[dt][rr * 4 + 2] * inv));
        pk.w = __builtin_bit_cast(unsigned short, (bf16)(accO[dt][rr * 4 + 3] * inv));
        *(ushort4*)(cp + dt * 32 + rr * 8 + hi * 4) = pk;
      }
  }
}

// ---------------------------------------------------------------------------
// Output GEMM (R6 known-good form): out = ctx·Wo^T + bo, f32 output.
// ---------------------------------------------------------------------------
__global__ __launch_bounds__(256, 2) void out_gemm(
    const bf16* __restrict__ A, const bf16* __restrict__ W,
    const float* __restrict__ bias, float* __restrict__ out) {
  __shared__ bf16 Ab[2][128 * 64];
  __shared__ bf16 Bb[2][128 * 64];

  const int tid  = threadIdx.x;
  const int wave = tid >> 6, lane = tid & 63;
  const int r = lane & 15, g = lane >> 4;

  const int wg = blockIdx.x;
  const int sw = ((wg & 7) << 6) | (wg >> 3);
  const int m0 = (sw >> 3) * 128, n0 = (sw & 7) * 128;
  const int wm = (wave >> 1) * 64, wn = (wave & 1) * 64;

  f32x4 acc[4][4] = {};

  const int srr = lane >> 3;
  const int scb = (lane & 7) * 16;
  const int swz = srr << 4;

#define STAGE2(buf, k0)                                                             \
  do {                                                                              \
    _Pragma("unroll") for (int i_ = 0; i_ < 4; ++i_) {                              \
      const int row_ = wave * 32 + i_ * 8 + srr;                                    \
      const char* as_ =                                                             \
          (const char*)(A + (size_t)(m0 + row_) * DIM + (k0)) + (scb ^ swz);        \
      GLOAD16(as_, (char*)&Ab[buf][0] + (wave * 32 + i_ * 8) * 128);                \
      const char* bs_ =                                                             \
          (const char*)(W + (size_t)(n0 + row_) * DIM + (k0)) + (scb ^ swz);        \
      GLOAD16(bs_, (char*)&Bb[buf][0] + (wave * 32 + i_ * 8) * 128);                \
    }                                                                               \
  } while (0)

  STAGE2(0, 0);
  __syncthreads();

  const int NK = DIM / 64;
  for (int it = 0; it < NK; ++it) {
    const int cur = it & 1;
    if (it + 1 < NK) STAGE2(cur ^ 1, (it + 1) * 64);

#pragma unroll
    for (int ks = 0; ks < 2; ++ks) {
      bf16x8 af[4], bfr[4];
#pragma unroll
      for (int mt = 0; mt < 4; ++mt) {
        const int mr = wm + mt * 16 + r;
        af[mt] = *(bf16x8*)((char*)&Ab[cur][0] + mr * 128 +
                            ((ks * 64 + g * 16) ^ ((mr & 7) << 4)));
      }
#pragma unroll
      for (int nt = 0; nt < 4; ++nt) {
        const int nr = wn + nt * 16 + r;
        bfr[nt] = *(bf16x8*)((char*)&Bb[cur][0] + nr * 128 +
                             ((ks * 64 + g * 16) ^ ((nr & 7) << 4)));
      }
#pragma unroll
      for (int mt = 0; mt < 4; ++mt)
#pragma unroll
        for (int nt = 0; nt < 4; ++nt)
          acc[mt][nt] = MFMA(af[mt], bfr[nt], acc[mt][nt]);
    }

    __syncthreads();
  }
#undef STAGE2

#pragma unroll
  for (int mt = 0; mt < 4; ++mt)
#pragma unroll
    for (int nt = 0; nt < 4; ++nt) {
      const int n = n0 + wn + nt * 16 + r;
      const float bn = bias[n];
#pragma unroll
      for (int i = 0; i < 4; ++i) {
        const int m = m0 + wm + mt * 16 + g * 4 + i;
        out[(size_t)m * DIM + n] = acc[mt][nt][i] + bn;
      }
    }
}

// ---------------------------------------------------------------------------
// kernel_launch
// ---------------------------------------------------------------------------
extern "C" void kernel_launch(void* const* d_in, const int* in_sizes, int n_in,
                              void* d_out, int out_size, void* d_ws, size_t ws_size,
                              hipStream_t stream) {
  const float* query  = (const float*)d_in[0];
  const float* key_in = (const float*)d_in[1];
  const float* value  = (const float*)d_in[2];
  const float* Wq = (const float*)d_in[3];
  const float* bq = (const float*)d_in[4];
  const float* Wk = (const float*)d_in[5];
  const float* bk = (const float*)d_in[6];
  const float* Wv = (const float*)d_in[7];
  const float* bv = (const float*)d_in[8];
  const float* Wo = (const float*)d_in[9];
  const float* bo = (const float*)d_in[10];

  // ws layout (72 MiB): 4 x 2MiB bf16 weights; 4 x 16MiB bf16 tensors.
  // C_b doubles as the bf16-activation staging buffer before attn runs.
  char* ws = (char*)d_ws;
  const size_t WSZ = (size_t)DIM * DIM * sizeof(bf16);
  const size_t TSZ = (size_t)BATCH * SEQ * DIM * sizeof(bf16);
  bf16* Wq_b = (bf16*)(ws);
  bf16* Wk_b = (bf16*)(ws + WSZ);
  bf16* Wv_b = (bf16*)(ws + 2 * WSZ);
  bf16* Wo_b = (bf16*)(ws + 3 * WSZ);
  bf16* Q_b  = (bf16*)(ws + 4 * WSZ);
  bf16* K_b  = (bf16*)(ws + 4 * WSZ + TSZ);
  bf16* Vt_b = (bf16*)(ws + 4 * WSZ + 2 * TSZ);
  bf16* C_b  = (bf16*)(ws + 4 * WSZ + 3 * TSZ);
  bf16* X_b  = C_b;  // staging alias: consumed before attn writes ctx

  cvt_w_kernel<<<dim3(DIM * DIM / (256 * 4), 4), 256, 0, stream>>>(
      Wq, Wk, Wv, Wo, Wq_b, Wk_b, Wv_b, Wo_b);

  const int XBLK = BATCH * SEQ * DIM / (256 * 8);  // 4096

  cvt_x_kernel<<<dim3(XBLK), 256, 0, stream>>>(query, X_b);
  proj_gemm<<<dim3(512), 256, 0, stream>>>(X_b, Wq_b, bq, Q_b, 0);

  cvt_x_kernel<<<dim3(XBLK), 256, 0, stream>>>(key_in, X_b);
  proj_gemm<<<dim3(512), 256, 0, stream>>>(X_b, Wk_b, bk, K_b, 1);

  cvt_x_kernel<<<dim3(XBLK), 256, 0, stream>>>(value, X_b);
  proj_gemm<<<dim3(512), 256, 0, stream>>>(X_b, Wv_b, bv, Vt_b, 2);

  attn_kernel<<<dim3(1024), 256, 0, stream>>>(Q_b, K_b, Vt_b, C_b);

  out_gemm<<<dim3(512), 256, 0, stream>>>(C_b, Wo_b, bo, (float*)d_out);
}

// Round 9
// 193.293 us; speedup vs baseline: 1.1300x; 1.1300x over previous
//
#include <hip/hip_runtime.h>
#include <hip/hip_bf16.h>
#include <stdint.h>

typedef __bf16 bf16;
typedef __bf16 bf16x8 __attribute__((ext_vector_type(8)));
typedef float f32x4 __attribute__((ext_vector_type(4)));
typedef float f32x16 __attribute__((ext_vector_type(16)));

#define BATCH 4
#define SEQ   2048
#define DIM   1024
#define NH    16
#define HD    64

// Q projection pre-scaled by (1/sqrt(HD)) * log2(e): softmax runs in exp2 domain.
#define QSCALE 0.18033688011112042f  // 0.125 * 1.4426950408889634

#define MFMA(a, b, c)   __builtin_amdgcn_mfma_f32_16x16x32_bf16((a), (b), (c), 0, 0, 0)
#define MFMA32(a, b, c) __builtin_amdgcn_mfma_f32_32x32x16_bf16((a), (b), (c), 0, 0, 0)

// global -> LDS direct copy, 16B per lane. LDS dest is wave-uniform base+lane*16.
#define GLOAD16(gsrc, ldst)                                                        \
  __builtin_amdgcn_global_load_lds(                                                \
      (__attribute__((address_space(1))) unsigned int*)(void*)(gsrc),              \
      (__attribute__((address_space(3))) unsigned int*)(ldst), 16, 0, 0)

static __device__ __forceinline__ float fast_exp2(float x) {
#if __has_builtin(__builtin_amdgcn_exp2f)
  return __builtin_amdgcn_exp2f(x);
#else
  return exp2f(x);
#endif
}

// ---------------------------------------------------------------------------
// Weight conversion: f32 -> bf16, 4 tensors of DIM*DIM each.
// ---------------------------------------------------------------------------
__global__ __launch_bounds__(256) void cvt_w_kernel(
    const float* __restrict__ w0, const float* __restrict__ w1,
    const float* __restrict__ w2, const float* __restrict__ w3,
    bf16* __restrict__ o0, bf16* __restrict__ o1,
    bf16* __restrict__ o2, bf16* __restrict__ o3) {
  const float* s;
  bf16* d;
  switch (blockIdx.y) {
    case 0: s = w0; d = o0; break;
    case 1: s = w1; d = o1; break;
    case 2: s = w2; d = o2; break;
    default: s = w3; d = o3; break;
  }
  const int i = (blockIdx.x * 256 + threadIdx.x) * 4;
  const float4 v = *(const float4*)(s + i);
  ushort4 o;
  o.x = __builtin_bit_cast(unsigned short, (bf16)v.x);
  o.y = __builtin_bit_cast(unsigned short, (bf16)v.y);
  o.z = __builtin_bit_cast(unsigned short, (bf16)v.z);
  o.w = __builtin_bit_cast(unsigned short, (bf16)v.w);
  *(ushort4*)((unsigned short*)d + i) = o;
}

// ---------------------------------------------------------------------------
// Projection GEMM (R5 form — best total-time config): C = A·W^T + bias.
// A: f32 staged DIRECTLY into LDS via global_load_lds; f32->bf16 conversion
// in the fragment-read path. W: bf16 via global_load_lds.
// Tile 128x128, BK=64, single-buffered (48 KiB LDS), two barriers per K-step,
// XCD-chunked block swizzle. Single dispatch, grid.z = 3 (Q, K, Vt).
// ---------------------------------------------------------------------------
struct ProjArgs {
  const float* A[3];
  const bf16*  W[3];
  const float* bias[3];
  bf16*        out[3];
};

__global__ __launch_bounds__(256, 3) void proj_gemm(ProjArgs p) {
  const int z = blockIdx.z;
  const float* __restrict__ A    = p.A[z];
  const bf16*  __restrict__ W    = p.W[z];
  const float* __restrict__ bias = p.bias[z];
  bf16*        __restrict__ out  = p.out[z];

  __shared__ float Af[128 * 64];  // [row 128][k 64] f32, 256B rows, swizzled
  __shared__ bf16  Bb[128 * 64];  // [row 128][k 64] bf16, 128B rows, swizzled

  const int tid  = threadIdx.x;
  const int wave = tid >> 6, lane = tid & 63;
  const int r = lane & 15, g = lane >> 4;

  const int wg = blockIdx.x;
  const int sw = ((wg & 7) << 6) | (wg >> 3);
  const int m0 = (sw >> 3) * 128, n0 = (sw & 7) * 128;
  const int wm = (wave >> 1) * 64, wn = (wave & 1) * 64;

  f32x4 acc[4][4] = {};

  const int a_sr = lane >> 4;
  const int a_cb = (lane & 15) * 16;
  const int b_sr = lane >> 3;
  const int b_cb = (lane & 7) * 16;

  const int NK = DIM / 64;
  for (int it = 0; it < NK; ++it) {
    const int k0 = it * 64;

#pragma unroll
    for (int i = 0; i < 8; ++i) {
      const int row = wave * 32 + i * 4 + a_sr;
      const char* src = (const char*)(A + (size_t)(m0 + row) * DIM + k0) +
                        (a_cb ^ ((row & 15) << 4));
      GLOAD16(src, (char*)Af + (wave * 32 + i * 4) * 256);
    }
#pragma unroll
    for (int i = 0; i < 4; ++i) {
      const int row = wave * 32 + i * 8 + b_sr;
      const char* src = (const char*)(W + (size_t)(n0 + row) * DIM + k0) +
                        (b_cb ^ ((row & 7) << 4));
      GLOAD16(src, (char*)Bb + (wave * 32 + i * 8) * 128);
    }
    __syncthreads();

#pragma unroll
    for (int ks = 0; ks < 2; ++ks) {
      bf16x8 af[4], bfr[4];
#pragma unroll
      for (int mt = 0; mt < 4; ++mt) {
        const int mr = wm + mt * 16 + r;
        const char* base = (const char*)Af + mr * 256;
        const int asw = (mr & 15) << 4;
        const f32x4 lo = *(const f32x4*)(base + ((ks * 128 + g * 32) ^ asw));
        const f32x4 hi = *(const f32x4*)(base + ((ks * 128 + g * 32 + 16) ^ asw));
        bf16x8 a;
        a[0] = (bf16)lo[0]; a[1] = (bf16)lo[1]; a[2] = (bf16)lo[2]; a[3] = (bf16)lo[3];
        a[4] = (bf16)hi[0]; a[5] = (bf16)hi[1]; a[6] = (bf16)hi[2]; a[7] = (bf16)hi[3];
        af[mt] = a;
      }
#pragma unroll
      for (int nt = 0; nt < 4; ++nt) {
        const int nr = wn + nt * 16 + r;
        bfr[nt] = *(bf16x8*)((char*)Bb + nr * 128 +
                             ((ks * 64 + g * 16) ^ ((nr & 7) << 4)));
      }
#pragma unroll
      for (int mt = 0; mt < 4; ++mt)
#pragma unroll
        for (int nt = 0; nt < 4; ++nt)
          acc[mt][nt] = MFMA(af[mt], bfr[nt], acc[mt][nt]);
    }

    __syncthreads();
  }

  if (z == 2) {
#pragma unroll
    for (int nt = 0; nt < 4; ++nt) {
      const int n = n0 + wn + nt * 16 + r;
      const float bn = bias[n];
#pragma unroll
      for (int mt = 0; mt < 4; ++mt) {
        const int m = m0 + wm + mt * 16 + g * 4;
        const int b = m >> 11, t = m & 2047;
        ushort4 pk;
        pk.x = __builtin_bit_cast(unsigned short, (bf16)(acc[mt][nt][0] + bn));
        pk.y = __builtin_bit_cast(unsigned short, (bf16)(acc[mt][nt][1] + bn));
        pk.z = __builtin_bit_cast(unsigned short, (bf16)(acc[mt][nt][2] + bn));
        pk.w = __builtin_bit_cast(unsigned short, (bf16)(acc[mt][nt][3] + bn));
        *(ushort4*)((unsigned short*)out + (((size_t)(b * DIM + n)) << 11) + t) = pk;
      }
    }
  } else {
    const float scale = (z == 0) ? QSCALE : 1.0f;
#pragma unroll
    for (int mt = 0; mt < 4; ++mt)
#pragma unroll
      for (int nt = 0; nt < 4; ++nt) {
        const int n = n0 + wn + nt * 16 + r;
        const float bn = bias[n];
#pragma unroll
        for (int i = 0; i < 4; ++i) {
          const int m = m0 + wm + mt * 16 + g * 4 + i;
          out[(size_t)m * DIM + n] = (bf16)((acc[mt][nt][i] + bn) * scale);
        }
      }
  }
}

// ---------------------------------------------------------------------------
// Fused attention, 32x32 swapped structure, fragment-linear K/V LDS
// (R8-verified layout: lane l's 16B at base+l*16, pi-permutation carried by
// per-lane GLOBAL source addresses -> 0 bank conflicts, no swizzle VALU),
// with R5's empirically-best sync structure: 2-buffer, __syncthreads/iter.
// ---------------------------------------------------------------------------
__global__ __launch_bounds__(256, 4) void attn_kernel(
    const bf16* __restrict__ Q, const bf16* __restrict__ K,
    const bf16* __restrict__ Vt, bf16* __restrict__ ctx) {
  // K: 2 buffers x 8 arrays (ka = kvt*4+st) x 1KB
  // V: 2 buffers x 8 arrays (va = dt*4+kvt*2+kb) x 1KB
  __shared__ alignas(16) char Kl[2 * 8192];
  __shared__ alignas(16) char Vl[2 * 8192];

  const int tid  = threadIdx.x;
  const int wave = tid >> 6, lane = tid & 63;
  const int l31 = lane & 31, hi = lane >> 5;

  // XCD-chunked swizzle: 8 heads (x16 q-blocks) per XCD
  const int wg  = blockIdx.x;
  const int swb = (wg & 7) * 128 + (wg >> 3);
  const int qblk = swb & 15, bh = swb >> 4;
  const int b = bh >> 4, h = bh & 15;
  const int q0 = qblk * 128 + wave * 32;

  // Q fragments (B operand): col q = lane&31, k(d) = st*16 + hi*8 + j
  bf16x8 qf[4];
  {
    const bf16* qp = Q + ((size_t)(b * SEQ + q0 + l31) * DIM + h * HD);
#pragma unroll
    for (int st = 0; st < 4; ++st)
      qf[st] = *(const bf16x8*)(qp + st * 16 + hi * 8);
  }

  f32x16 accO[2] = {};
  float m_i = -3e38f, l_i = 0.0f;

  const char* Kbase = (const char*)(K + (size_t)(b * SEQ) * DIM + h * HD);
  const char* Vbase = (const char*)(Vt + (size_t)(b * DIM + h * HD) * SEQ);

  // pi: swap bits 2,3 of the kv row (S^T C-layout -> PV B-operand order)
  const int t_ = (l31 >> 2) & 3;
  const int pl = (t_ == 1 || t_ == 2) ? (l31 ^ 12) : l31;

  // Per-wave staging: wave w owns K arrays {2w,2w+1} and V arrays {2w,2w+1}.
  int ksrc[2], kdst[2], vsrc[2], vdst[2];
#pragma unroll
  for (int i = 0; i < 2; ++i) {
    const int ka = wave * 2 + i;             // 0..7
    const int kvt = ka >> 2, st = ka & 3;
    ksrc[i] = ((kvt * 32 + pl) * DIM + st * 16 + hi * 8) * 2;
    kdst[i] = ka * 1024;
    const int va = wave * 2 + i;
    const int dt = va >> 2, kvt2 = (va >> 1) & 1, kb = va & 1;
    vsrc[i] = ((dt * 32 + l31) * SEQ + kvt2 * 32 + kb * 16 + hi * 8) * 2;
    vdst[i] = va * 1024;
  }

#define STAGE(buf, kv0)                                                             \
  do {                                                                              \
    _Pragma("unroll") for (int i_ = 0; i_ < 2; ++i_) {                              \
      GLOAD16(Kbase + (size_t)(kv0) * (2 * DIM) + ksrc[i_],                         \
              Kl + (buf) * 8192 + kdst[i_]);                                        \
      GLOAD16(Vbase + (size_t)(kv0) * 2 + vsrc[i_],                                 \
              Vl + (buf) * 8192 + vdst[i_]);                                        \
    }                                                                               \
  } while (0)

  STAGE(0, 0);
  __syncthreads();

  const int NIT = SEQ / 64;
  for (int it = 0; it < NIT; ++it) {
    const int cur = it & 1;
    if (it + 1 < NIT) STAGE(cur ^ 1, (it + 1) * 64);

    // --- S^T = K·Q : 2 kv-tiles x 4 k-steps, fragment-linear reads ---
    const char* kbp = Kl + cur * 8192 + lane * 16;
    f32x16 s[2] = {};
    __builtin_amdgcn_s_setprio(1);
#pragma unroll
    for (int kvt = 0; kvt < 2; ++kvt)
#pragma unroll
      for (int st = 0; st < 4; ++st) {
        const bf16x8 kf = *(const bf16x8*)(kbp + (kvt * 4 + st) * 1024);
        s[kvt] = MFMA32(kf, qf[st], s[kvt]);
      }
    __builtin_amdgcn_s_setprio(0);

    // --- tile max, tree (depth 5) ---
    float pm;
    {
      f32x16 m16;
#pragma unroll
      for (int e = 0; e < 16; ++e) m16[e] = fmaxf(s[0][e], s[1][e]);
      f32x4 m4;
#pragma unroll
      for (int e = 0; e < 4; ++e)
        m4[e] = fmaxf(fmaxf(m16[e], m16[e + 4]), fmaxf(m16[e + 8], m16[e + 12]));
      pm = fmaxf(fmaxf(m4[0], m4[1]), fmaxf(m4[2], m4[3]));
      pm = fmaxf(pm, __shfl_xor(pm, 32));
    }

    // --- defer-max: rescale only when running max grew by > 8 (log2) ---
    if (__any(pm > m_i + 8.0f)) {
      const float mn = fmaxf(m_i, pm);
      const float alpha = fast_exp2(m_i - mn);
      m_i = mn;
      l_i *= alpha;
#pragma unroll
      for (int dt = 0; dt < 2; ++dt)
#pragma unroll
        for (int e = 0; e < 16; ++e) accO[dt][e] *= alpha;
    }

    // --- P = exp2(S - m); row-sum as tree ---
#pragma unroll
    for (int kvt = 0; kvt < 2; ++kvt)
#pragma unroll
      for (int e = 0; e < 16; ++e) s[kvt][e] = fast_exp2(s[kvt][e] - m_i);
    {
      f32x16 t16;
#pragma unroll
      for (int e = 0; e < 16; ++e) t16[e] = s[0][e] + s[1][e];
      f32x4 t4;
#pragma unroll
      for (int e = 0; e < 4; ++e)
        t4[e] = (t16[e] + t16[e + 4]) + (t16[e + 8] + t16[e + 12]);
      float rs = (t4[0] + t4[1]) + (t4[2] + t4[3]);
      l_i += rs + __shfl_xor(rs, 32);
    }

    // --- pack P to bf16 frags (in-register, thanks to pi-permuted K) ---
    bf16x8 pa[2][2];
#pragma unroll
    for (int kvt = 0; kvt < 2; ++kvt)
#pragma unroll
      for (int kb = 0; kb < 2; ++kb)
#pragma unroll
        for (int j = 0; j < 8; ++j)
          pa[kvt][kb][j] = (bf16)s[kvt][kb * 8 + j];

    // --- O^T += V^T · P, fragment-linear reads ---
    const char* vbp = Vl + cur * 8192 + lane * 16;
    __builtin_amdgcn_s_setprio(1);
#pragma unroll
    for (int dt = 0; dt < 2; ++dt)
#pragma unroll
      for (int kvt = 0; kvt < 2; ++kvt)
#pragma unroll
        for (int kb = 0; kb < 2; ++kb) {
          const bf16x8 vf =
              *(const bf16x8*)(vbp + (dt * 4 + kvt * 2 + kb) * 1024);
          accO[dt] = MFMA32(vf, pa[kvt][kb], accO[dt]);
        }
    __builtin_amdgcn_s_setprio(0);

    __syncthreads();  // drains staging for tile it+1; frees buf for it+2
  }
#undef STAGE

  // --- normalize and write ctx: lane owns q = q0+l31, d = dt*32+rr*8+4hi+c ---
  {
    const float inv = 1.0f / l_i;
    bf16* cp = ctx + (size_t)(b * SEQ + q0 + l31) * DIM + h * HD;
#pragma unroll
    for (int dt = 0; dt < 2; ++dt)
#pragma unroll
      for (int rr = 0; rr < 4; ++rr) {
        ushort4 pk;
        pk.x = __builtin_bit_cast(unsigned short, (bf16)(accO[dt][rr * 4 + 0] * inv));
        pk.y = __builtin_bit_cast(unsigned short, (bf16)(accO[dt][rr * 4 + 1] * inv));
        pk.z = __builtin_bit_cast(unsigned short, (bf16)(accO[dt][rr * 4 + 2] * inv));
        pk.w = __builtin_bit_cast(unsigned short, (bf16)(accO[dt][rr * 4 + 3] * inv));
        *(ushort4*)(cp + dt * 32 + rr * 8 + hi * 4) = pk;
      }
  }
}

// ---------------------------------------------------------------------------
// Output GEMM (R5 form): out = ctx·Wo^T + bo, f32 output.
// BK=64 / dbuf / __syncthreads; both operands GLOAD16.
// ---------------------------------------------------------------------------
__global__ __launch_bounds__(256, 2) void out_gemm(
    const bf16* __restrict__ A, const bf16* __restrict__ W,
    const float* __restrict__ bias, float* __restrict__ out) {
  __shared__ bf16 Ab[2][128 * 64];
  __shared__ bf16 Bb[2][128 * 64];

  const int tid  = threadIdx.x;
  const int wave = tid >> 6, lane = tid & 63;
  const int r = lane & 15, g = lane >> 4;

  const int wg = blockIdx.x;
  const int sw = ((wg & 7) << 6) | (wg >> 3);
  const int m0 = (sw >> 3) * 128, n0 = (sw & 7) * 128;
  const int wm = (wave >> 1) * 64, wn = (wave & 1) * 64;

  f32x4 acc[4][4] = {};

  const int srr = lane >> 3;
  const int scb = (lane & 7) * 16;
  const int swz = srr << 4;

#define STAGE2(buf, k0)                                                             \
  do {                                                                              \
    _Pragma("unroll") for (int i_ = 0; i_ < 4; ++i_) {                              \
      const int row_ = wave * 32 + i_ * 8 + srr;                                    \
      const char* as_ =                                                             \
          (const char*)(A + (size_t)(m0 + row_) * DIM + (k0)) + (scb ^ swz);        \
      GLOAD16(as_, (char*)&Ab[buf][0] + (wave * 32 + i_ * 8) * 128);                \
      const char* bs_ =                                                             \
          (const char*)(W + (size_t)(n0 + row_) * DIM + (k0)) + (scb ^ swz);        \
      GLOAD16(bs_, (char*)&Bb[buf][0] + (wave * 32 + i_ * 8) * 128);                \
    }                                                                               \
  } while (0)

  STAGE2(0, 0);
  __syncthreads();

  const int NK = DIM / 64;
  for (int it = 0; it < NK; ++it) {
    const int cur = it & 1;
    if (it + 1 < NK) STAGE2(cur ^ 1, (it + 1) * 64);

#pragma unroll
    for (int ks = 0; ks < 2; ++ks) {
      bf16x8 af[4], bfr[4];
#pragma unroll
      for (int mt = 0; mt < 4; ++mt) {
        const int mr = wm + mt * 16 + r;
        af[mt] = *(bf16x8*)((char*)&Ab[cur][0] + mr * 128 +
                            ((ks * 64 + g * 16) ^ ((mr & 7) << 4)));
      }
#pragma unroll
      for (int nt = 0; nt < 4; ++nt) {
        const int nr = wn + nt * 16 + r;
        bfr[nt] = *(bf16x8*)((char*)&Bb[cur][0] + nr * 128 +
                             ((ks * 64 + g * 16) ^ ((nr & 7) << 4)));
      }
#pragma unroll
      for (int mt = 0; mt < 4; ++mt)
#pragma unroll
        for (int nt = 0; nt < 4; ++nt)
          acc[mt][nt] = MFMA(af[mt], bfr[nt], acc[mt][nt]);
    }

    __syncthreads();
  }
#undef STAGE2

#pragma unroll
  for (int mt = 0; mt < 4; ++mt)
#pragma unroll
    for (int nt = 0; nt < 4; ++nt) {
      const int n = n0 + wn + nt * 16 + r;
      const float bn = bias[n];
#pragma unroll
      for (int i = 0; i < 4; ++i) {
        const int m = m0 + wm + mt * 16 + g * 4 + i;
        out[(size_t)m * DIM + n] = acc[mt][nt][i] + bn;
      }
    }
}

// ---------------------------------------------------------------------------
// kernel_launch (R5 sequence: no cvt_x round-trip, single 3-z proj dispatch)
// ---------------------------------------------------------------------------
extern "C" void kernel_launch(void* const* d_in, const int* in_sizes, int n_in,
                              void* d_out, int out_size, void* d_ws, size_t ws_size,
                              hipStream_t stream) {
  const float* query  = (const float*)d_in[0];
  const float* key_in = (const float*)d_in[1];
  const float* value  = (const float*)d_in[2];
  const float* Wq = (const float*)d_in[3];
  const float* bq = (const float*)d_in[4];
  const float* Wk = (const float*)d_in[5];
  const float* bk = (const float*)d_in[6];
  const float* Wv = (const float*)d_in[7];
  const float* bv = (const float*)d_in[8];
  const float* Wo = (const float*)d_in[9];
  const float* bo = (const float*)d_in[10];

  char* ws = (char*)d_ws;
  const size_t WSZ = (size_t)DIM * DIM * sizeof(bf16);
  const size_t TSZ = (size_t)BATCH * SEQ * DIM * sizeof(bf16);
  bf16* Wq_b = (bf16*)(ws);
  bf16* Wk_b = (bf16*)(ws + WSZ);
  bf16* Wv_b = (bf16*)(ws + 2 * WSZ);
  bf16* Wo_b = (bf16*)(ws + 3 * WSZ);
  bf16* Q_b  = (bf16*)(ws + 4 * WSZ);
  bf16* K_b  = (bf16*)(ws + 4 * WSZ + TSZ);
  bf16* Vt_b = (bf16*)(ws + 4 * WSZ + 2 * TSZ);
  bf16* C_b  = (bf16*)(ws + 4 * WSZ + 3 * TSZ);

  cvt_w_kernel<<<dim3(DIM * DIM / (256 * 4), 4), 256, 0, stream>>>(
      Wq, Wk, Wv, Wo, Wq_b, Wk_b, Wv_b, Wo_b);

  ProjArgs pa;
  pa.A[0] = query; pa.A[1] = key_in; pa.A[2] = value;
  pa.W[0] = Wq_b;  pa.W[1] = Wk_b;   pa.W[2] = Wv_b;
  pa.bias[0] = bq; pa.bias[1] = bk;  pa.bias[2] = bv;
  pa.out[0] = Q_b; pa.out[1] = K_b;  pa.out[2] = Vt_b;
  proj_gemm<<<dim3(512, 1, 3), 256, 0, stream>>>(pa);

  attn_kernel<<<dim3(1024), 256, 0, stream>>>(Q_b, K_b, Vt_b, C_b);

  out_gemm<<<dim3(512), 256, 0, stream>>>(C_b, Wo_b, bo, (float*)d_out);
}

// Round 10
// 182.951 us; speedup vs baseline: 1.1938x; 1.0565x over previous
//
#include <hip/hip_runtime.h>
#include <hip/hip_bf16.h>
#include <stdint.h>

typedef __bf16 bf16;
typedef __bf16 bf16x8 __attribute__((ext_vector_type(8)));
typedef float f32x4 __attribute__((ext_vector_type(4)));
typedef float f32x16 __attribute__((ext_vector_type(16)));

#define BATCH 4
#define SEQ   2048
#define DIM   1024
#define NH    16
#define HD    64

// Q projection pre-scaled by (1/sqrt(HD)) * log2(e): softmax runs in exp2 domain.
#define QSCALE 0.18033688011112042f  // 0.125 * 1.4426950408889634

#define MFMA(a, b, c)   __builtin_amdgcn_mfma_f32_16x16x32_bf16((a), (b), (c), 0, 0, 0)
#define MFMA32(a, b, c) __builtin_amdgcn_mfma_f32_32x32x16_bf16((a), (b), (c), 0, 0, 0)

// global -> LDS direct copy, 16B per lane. LDS dest is wave-uniform base+lane*16.
#define GLOAD16(gsrc, ldst)                                                        \
  __builtin_amdgcn_global_load_lds(                                                \
      (__attribute__((address_space(1))) unsigned int*)(void*)(gsrc),              \
      (__attribute__((address_space(3))) unsigned int*)(ldst), 16, 0, 0)

static __device__ __forceinline__ float fast_exp2(float x) {
#if __has_builtin(__builtin_amdgcn_exp2f)
  return __builtin_amdgcn_exp2f(x);
#else
  return exp2f(x);
#endif
}

// ---------------------------------------------------------------------------
// Weight conversion: f32 -> bf16, 4 tensors of DIM*DIM each.
// ---------------------------------------------------------------------------
__global__ __launch_bounds__(256) void cvt_w_kernel(
    const float* __restrict__ w0, const float* __restrict__ w1,
    const float* __restrict__ w2, const float* __restrict__ w3,
    bf16* __restrict__ o0, bf16* __restrict__ o1,
    bf16* __restrict__ o2, bf16* __restrict__ o3) {
  const float* s;
  bf16* d;
  switch (blockIdx.y) {
    case 0: s = w0; d = o0; break;
    case 1: s = w1; d = o1; break;
    case 2: s = w2; d = o2; break;
    default: s = w3; d = o3; break;
  }
  const int i = (blockIdx.x * 256 + threadIdx.x) * 4;
  const float4 v = *(const float4*)(s + i);
  ushort4 o;
  o.x = __builtin_bit_cast(unsigned short, (bf16)v.x);
  o.y = __builtin_bit_cast(unsigned short, (bf16)v.y);
  o.z = __builtin_bit_cast(unsigned short, (bf16)v.z);
  o.w = __builtin_bit_cast(unsigned short, (bf16)v.w);
  *(ushort4*)((unsigned short*)d + i) = o;
}

// ---------------------------------------------------------------------------
// Projection GEMM: C[m,n] = sum_k A[m,k] * W[n,k] + bias[n]   (nn.Linear)
// A: f32 staged DIRECTLY into LDS via global_load_lds; f32->bf16 conversion
// in the fragment-read path. W: bf16 via global_load_lds.
// Tile 128x128, BK=64, single-buffered (48 KiB LDS), two barriers per K-step,
// XCD-chunked block swizzle. Single dispatch, grid.z = 3 (Q, K, Vt).
// ---------------------------------------------------------------------------
struct ProjArgs {
  const float* A[3];
  const bf16*  W[3];
  const float* bias[3];
  bf16*        out[3];
};

__global__ __launch_bounds__(256, 3) void proj_gemm(ProjArgs p) {
  const int z = blockIdx.z;
  const float* __restrict__ A    = p.A[z];
  const bf16*  __restrict__ W    = p.W[z];
  const float* __restrict__ bias = p.bias[z];
  bf16*        __restrict__ out  = p.out[z];

  __shared__ float Af[128 * 64];  // [row 128][k 64] f32, 256B rows, swizzled
  __shared__ bf16  Bb[128 * 64];  // [row 128][k 64] bf16, 128B rows, swizzled

  const int tid  = threadIdx.x;
  const int wave = tid >> 6, lane = tid & 63;
  const int r = lane & 15, g = lane >> 4;

  const int wg = blockIdx.x;
  const int sw = ((wg & 7) << 6) | (wg >> 3);
  const int m0 = (sw >> 3) * 128, n0 = (sw & 7) * 128;
  const int wm = (wave >> 1) * 64, wn = (wave & 1) * 64;

  f32x4 acc[4][4] = {};

  const int a_sr = lane >> 4;
  const int a_cb = (lane & 15) * 16;
  const int b_sr = lane >> 3;
  const int b_cb = (lane & 7) * 16;

  const int NK = DIM / 64;
  for (int it = 0; it < NK; ++it) {
    const int k0 = it * 64;

#pragma unroll
    for (int i = 0; i < 8; ++i) {
      const int row = wave * 32 + i * 4 + a_sr;
      const char* src = (const char*)(A + (size_t)(m0 + row) * DIM + k0) +
                        (a_cb ^ ((row & 15) << 4));
      GLOAD16(src, (char*)Af + (wave * 32 + i * 4) * 256);
    }
#pragma unroll
    for (int i = 0; i < 4; ++i) {
      const int row = wave * 32 + i * 8 + b_sr;
      const char* src = (const char*)(W + (size_t)(n0 + row) * DIM + k0) +
                        (b_cb ^ ((row & 7) << 4));
      GLOAD16(src, (char*)Bb + (wave * 32 + i * 8) * 128);
    }
    __syncthreads();

#pragma unroll
    for (int ks = 0; ks < 2; ++ks) {
      bf16x8 af[4], bfr[4];
#pragma unroll
      for (int mt = 0; mt < 4; ++mt) {
        const int mr = wm + mt * 16 + r;
        const char* base = (const char*)Af + mr * 256;
        const int asw = (mr & 15) << 4;
        const f32x4 lo = *(const f32x4*)(base + ((ks * 128 + g * 32) ^ asw));
        const f32x4 hi = *(const f32x4*)(base + ((ks * 128 + g * 32 + 16) ^ asw));
        bf16x8 a;
        a[0] = (bf16)lo[0]; a[1] = (bf16)lo[1]; a[2] = (bf16)lo[2]; a[3] = (bf16)lo[3];
        a[4] = (bf16)hi[0]; a[5] = (bf16)hi[1]; a[6] = (bf16)hi[2]; a[7] = (bf16)hi[3];
        af[mt] = a;
      }
#pragma unroll
      for (int nt = 0; nt < 4; ++nt) {
        const int nr = wn + nt * 16 + r;
        bfr[nt] = *(bf16x8*)((char*)Bb + nr * 128 +
                             ((ks * 64 + g * 16) ^ ((nr & 7) << 4)));
      }
#pragma unroll
      for (int mt = 0; mt < 4; ++mt)
#pragma unroll
        for (int nt = 0; nt < 4; ++nt)
          acc[mt][nt] = MFMA(af[mt], bfr[nt], acc[mt][nt]);
    }

    __syncthreads();
  }

  if (z == 2) {
#pragma unroll
    for (int nt = 0; nt < 4; ++nt) {
      const int n = n0 + wn + nt * 16 + r;
      const float bn = bias[n];
#pragma unroll
      for (int mt = 0; mt < 4; ++mt) {
        const int m = m0 + wm + mt * 16 + g * 4;
        const int b = m >> 11, t = m & 2047;
        ushort4 pk;
        pk.x = __builtin_bit_cast(unsigned short, (bf16)(acc[mt][nt][0] + bn));
        pk.y = __builtin_bit_cast(unsigned short, (bf16)(acc[mt][nt][1] + bn));
        pk.z = __builtin_bit_cast(unsigned short, (bf16)(acc[mt][nt][2] + bn));
        pk.w = __builtin_bit_cast(unsigned short, (bf16)(acc[mt][nt][3] + bn));
        *(ushort4*)((unsigned short*)out + (((size_t)(b * DIM + n)) << 11) + t) = pk;
      }
    }
  } else {
    const float scale = (z == 0) ? QSCALE : 1.0f;
#pragma unroll
    for (int mt = 0; mt < 4; ++mt)
#pragma unroll
      for (int nt = 0; nt < 4; ++nt) {
        const int n = n0 + wn + nt * 16 + r;
        const float bn = bias[n];
#pragma unroll
        for (int i = 0; i < 4; ++i) {
          const int m = m0 + wm + mt * 16 + g * 4 + i;
          out[(size_t)m * DIM + n] = (bf16)((acc[mt][nt][i] + bn) * scale);
        }
      }
  }
}

// ---------------------------------------------------------------------------
// Fused attention, 32x32 swapped structure (R5-verbatim, best measured).
// Wave = 32 q-rows (q = lane&31); block = 4 waves = 128 q per (b,h).
// KV tiles of 64, double-buffered XOR-swizzled row-major LDS (128B-coalesced
// staging), 1 __syncthreads/iter. S^T = mfma_32x32x16(K, Q); K rows staged
// PI-PERMUTED (pi(c)=c^12 for middle 4-blocks) so P stays in registers.
// O^T = mfma_32x32x16(V^T, P). exp2-domain online softmax, defer-max THR=8.
// ---------------------------------------------------------------------------
__global__ __launch_bounds__(256, 4) void attn_kernel(
    const bf16* __restrict__ Q, const bf16* __restrict__ K,
    const bf16* __restrict__ Vt, bf16* __restrict__ ctx) {
  __shared__ bf16 Kb[2][64 * 64];   // [kv 64][d 64], 128B rows, XOR-swizzled
  __shared__ bf16 Vb[2][64 * 64];   // [d 64][kv 64], 128B rows, XOR-swizzled

  const int tid  = threadIdx.x;
  const int wave = tid >> 6, lane = tid & 63;
  const int l31 = lane & 31, hi = lane >> 5;

  const int wg  = blockIdx.x;
  const int swb = (wg & 7) * 128 + (wg >> 3);
  const int qblk = swb & 15, bh = swb >> 4;
  const int b = bh >> 4, h = bh & 15;
  const int q0 = qblk * 128 + wave * 32;

  bf16x8 qf[4];
  {
    const bf16* qp = Q + ((size_t)(b * SEQ + q0 + l31) * DIM + h * HD);
#pragma unroll
    for (int st = 0; st < 4; ++st)
      qf[st] = *(const bf16x8*)(qp + st * 16 + hi * 8);
  }

  f32x16 accO[2] = {};
  float m_i = -3e38f, l_i = 0.0f;

  const bf16* Kbase = K + (size_t)(b * SEQ) * DIM + h * HD;
  const bf16* Vbase = Vt + (size_t)(b * DIM + h * HD) * SEQ;

  const int srr = lane >> 3;        // staged sub-row within 8-row group
  const int scb = (lane & 7) * 16;  // staged byte col
  const int swz = srr << 4;         // == (row&7)<<4 for staged rows

  // K source rows: pi-permuted within each 32-row half (pi(c)=c^12 for
  // middle 4-blocks), so S^T registers land in PV B-operand order.
  int koff[2], voff[2], kdst[2], vdst[2];
#pragma unroll
  for (int i = 0; i < 2; ++i) {
    const int rl = wave * 16 + i * 8 + srr;
    const int r32 = rl & 31;
    const int t = (r32 >> 2) & 3;
    const int rsrc = (rl & 32) + ((t == 1 || t == 2) ? (r32 ^ 12) : r32);
    koff[i] = rsrc * (DIM * 2) + (scb ^ swz);
    voff[i] = rl * (SEQ * 2) + (scb ^ swz);
    kdst[i] = (wave * 16 + i * 8) * 128;
    vdst[i] = (wave * 16 + i * 8) * 128;
  }

#define STAGE(buf, kv0)                                                             \
  do {                                                                              \
    _Pragma("unroll") for (int i_ = 0; i_ < 2; ++i_) {                              \
      GLOAD16((const char*)Kbase + (size_t)(kv0) * (DIM * 2) + koff[i_],            \
              (char*)&Kb[buf][0] + kdst[i_]);                                       \
      GLOAD16((const char*)Vbase + (size_t)(kv0) * 2 + voff[i_],                    \
              (char*)&Vb[buf][0] + vdst[i_]);                                       \
    }                                                                               \
  } while (0)

  STAGE(0, 0);
  __syncthreads();

  const int NIT = SEQ / 64;
  for (int it = 0; it < NIT; ++it) {
    const int cur = it & 1;
    if (it + 1 < NIT) STAGE(cur ^ 1, (it + 1) * 64);

    // --- S^T = K·Q : 2 kv-tiles x 4 k-steps of mfma_32x32x16 ---
    f32x16 s[2] = {};
    __builtin_amdgcn_s_setprio(1);
#pragma unroll
    for (int kvt = 0; kvt < 2; ++kvt) {
      const int row = kvt * 32 + l31;
      const char* kb = (const char*)&Kb[cur][0] + row * 128;
      const int rsw = (row & 7) << 4;
#pragma unroll
      for (int st = 0; st < 4; ++st) {
        const bf16x8 kf = *(const bf16x8*)(kb + ((st * 32 + hi * 16) ^ rsw));
        s[kvt] = MFMA32(kf, qf[st], s[kvt]);
      }
    }
    __builtin_amdgcn_s_setprio(0);

    // --- row max: lane-local + cross-half merge ---
    float pm = s[0][0];
#pragma unroll
    for (int kvt = 0; kvt < 2; ++kvt)
#pragma unroll
      for (int e = 0; e < 16; ++e)
        if (kvt || e) pm = fmaxf(pm, s[kvt][e]);
    pm = fmaxf(pm, __shfl_xor(pm, 32));

    // --- defer-max: rescale only when running max grew by > 8 (log2) ---
    if (__any(pm > m_i + 8.0f)) {
      const float mn = fmaxf(m_i, pm);
      const float alpha = fast_exp2(m_i - mn);
      m_i = mn;
      l_i *= alpha;
#pragma unroll
      for (int dt = 0; dt < 2; ++dt)
#pragma unroll
        for (int e = 0; e < 16; ++e) accO[dt][e] *= alpha;
    }

    // --- P = exp2(S - m), row-sum ---
    float rs = 0.0f;
#pragma unroll
    for (int kvt = 0; kvt < 2; ++kvt)
#pragma unroll
      for (int e = 0; e < 16; ++e) {
        s[kvt][e] = fast_exp2(s[kvt][e] - m_i);
        rs += s[kvt][e];
      }
    l_i += rs + __shfl_xor(rs, 32);

    // --- pack P to bf16 frags (in-register, thanks to pi-permuted K) ---
    bf16x8 pa[2][2];
#pragma unroll
    for (int kvt = 0; kvt < 2; ++kvt)
#pragma unroll
      for (int kb = 0; kb < 2; ++kb)
#pragma unroll
        for (int j = 0; j < 8; ++j)
          pa[kvt][kb][j] = (bf16)s[kvt][kb * 8 + j];

    // --- O^T += V^T · P ---
    __builtin_amdgcn_s_setprio(1);
#pragma unroll
    for (int dt = 0; dt < 2; ++dt) {
      const int row = dt * 32 + l31;
      const char* vb = (const char*)&Vb[cur][0] + row * 128;
      const int rsw = (row & 7) << 4;
#pragma unroll
      for (int kvt = 0; kvt < 2; ++kvt)
#pragma unroll
        for (int kb = 0; kb < 2; ++kb) {
          const bf16x8 vf =
              *(const bf16x8*)(vb + ((kvt * 64 + kb * 32 + hi * 16) ^ rsw));
          accO[dt] = MFMA32(vf, pa[kvt][kb], accO[dt]);
        }
    }
    __builtin_amdgcn_s_setprio(0);

    __syncthreads();  // drains vmcnt(0): next tile's staging complete
  }
#undef STAGE

  // --- normalize and write ctx: lane owns q = q0+l31, d = dt*32+rr*8+4hi+c ---
  {
    const float inv = 1.0f / l_i;
    bf16* cp = ctx + (size_t)(b * SEQ + q0 + l31) * DIM + h * HD;
#pragma unroll
    for (int dt = 0; dt < 2; ++dt)
#pragma unroll
      for (int rr = 0; rr < 4; ++rr) {
        ushort4 pk;
        pk.x = __builtin_bit_cast(unsigned short, (bf16)(accO[dt][rr * 4 + 0] * inv));
        pk.y = __builtin_bit_cast(unsigned short, (bf16)(accO[dt][rr * 4 + 1] * inv));
        pk.z = __builtin_bit_cast(unsigned short, (bf16)(accO[dt][rr * 4 + 2] * inv));
        pk.w = __builtin_bit_cast(unsigned short, (bf16)(accO[dt][rr * 4 + 3] * inv));
        *(ushort4*)(cp + dt * 32 + rr * 8 + hi * 4) = pk;
      }
  }
}

// ---------------------------------------------------------------------------
// Output GEMM: out[m,n] = sum_k ctx[m,k] * Wo[n,k] + bo[n], f32 output.
// BK=64 / dbuf / __syncthreads; both operands GLOAD16.
// ---------------------------------------------------------------------------
__global__ __launch_bounds__(256, 2) void out_gemm(
    const bf16* __restrict__ A, const bf16* __restrict__ W,
    const float* __restrict__ bias, float* __restrict__ out) {
  __shared__ bf16 Ab[2][128 * 64];
  __shared__ bf16 Bb[2][128 * 64];

  const int tid  = threadIdx.x;
  const int wave = tid >> 6, lane = tid & 63;
  const int r = lane & 15, g = lane >> 4;

  const int wg = blockIdx.x;
  const int sw = ((wg & 7) << 6) | (wg >> 3);
  const int m0 = (sw >> 3) * 128, n0 = (sw & 7) * 128;
  const int wm = (wave >> 1) * 64, wn = (wave & 1) * 64;

  f32x4 acc[4][4] = {};

  const int srr = lane >> 3;
  const int scb = (lane & 7) * 16;
  const int swz = srr << 4;

#define STAGE2(buf, k0)                                                             \
  do {                                                                              \
    _Pragma("unroll") for (int i_ = 0; i_ < 4; ++i_) {                              \
      const int row_ = wave * 32 + i_ * 8 + srr;                                    \
      const char* as_ =                                                             \
          (const char*)(A + (size_t)(m0 + row_) * DIM + (k0)) + (scb ^ swz);        \
      GLOAD16(as_, (char*)&Ab[buf][0] + (wave * 32 + i_ * 8) * 128);                \
      const char* bs_ =                                                             \
          (const char*)(W + (size_t)(n0 + row_) * DIM + (k0)) + (scb ^ swz);        \
      GLOAD16(bs_, (char*)&Bb[buf][0] + (wave * 32 + i_ * 8) * 128);                \
    }                                                                               \
  } while (0)

  STAGE2(0, 0);
  __syncthreads();

  const int NK = DIM / 64;
  for (int it = 0; it < NK; ++it) {
    const int cur = it & 1;
    if (it + 1 < NK) STAGE2(cur ^ 1, (it + 1) * 64);

#pragma unroll
    for (int ks = 0; ks < 2; ++ks) {
      bf16x8 af[4], bfr[4];
#pragma unroll
      for (int mt = 0; mt < 4; ++mt) {
        const int mr = wm + mt * 16 + r;
        af[mt] = *(bf16x8*)((char*)&Ab[cur][0] + mr * 128 +
                            ((ks * 64 + g * 16) ^ ((mr & 7) << 4)));
      }
#pragma unroll
      for (int nt = 0; nt < 4; ++nt) {
        const int nr = wn + nt * 16 + r;
        bfr[nt] = *(bf16x8*)((char*)&Bb[cur][0] + nr * 128 +
                             ((ks * 64 + g * 16) ^ ((nr & 7) << 4)));
      }
#pragma unroll
      for (int mt = 0; mt < 4; ++mt)
#pragma unroll
        for (int nt = 0; nt < 4; ++nt)
          acc[mt][nt] = MFMA(af[mt], bfr[nt], acc[mt][nt]);
    }

    __syncthreads();
  }
#undef STAGE2

#pragma unroll
  for (int mt = 0; mt < 4; ++mt)
#pragma unroll
    for (int nt = 0; nt < 4; ++nt) {
      const int n = n0 + wn + nt * 16 + r;
      const float bn = bias[n];
#pragma unroll
      for (int i = 0; i < 4; ++i) {
        const int m = m0 + wm + mt * 16 + g * 4 + i;
        out[(size_t)m * DIM + n] = acc[mt][nt][i] + bn;
      }
    }
}

// ---------------------------------------------------------------------------
// kernel_launch (R5 sequence: no cvt_x round-trip, single 3-z proj dispatch)
// ---------------------------------------------------------------------------
extern "C" void kernel_launch(void* const* d_in, const int* in_sizes, int n_in,
                              void* d_out, int out_size, void* d_ws, size_t ws_size,
                              hipStream_t stream) {
  const float* query  = (const float*)d_in[0];
  const float* key_in = (const float*)d_in[1];
  const float* value  = (const float*)d_in[2];
  const float* Wq = (const float*)d_in[3];
  const float* bq = (const float*)d_in[4];
  const float* Wk = (const float*)d_in[5];
  const float* bk = (const float*)d_in[6];
  const float* Wv = (const float*)d_in[7];
  const float* bv = (const float*)d_in[8];
  const float* Wo = (const float*)d_in[9];
  const float* bo = (const float*)d_in[10];

  char* ws = (char*)d_ws;
  const size_t WSZ = (size_t)DIM * DIM * sizeof(bf16);
  const size_t TSZ = (size_t)BATCH * SEQ * DIM * sizeof(bf16);
  bf16* Wq_b = (bf16*)(ws);
  bf16* Wk_b = (bf16*)(ws + WSZ);
  bf16* Wv_b = (bf16*)(ws + 2 * WSZ);
  bf16* Wo_b = (bf16*)(ws + 3 * WSZ);
  bf16* Q_b  = (bf16*)(ws + 4 * WSZ);
  bf16* K_b  = (bf16*)(ws + 4 * WSZ + TSZ);
  bf16* Vt_b = (bf16*)(ws + 4 * WSZ + 2 * TSZ);
  bf16* C_b  = (bf16*)(ws + 4 * WSZ + 3 * TSZ);

  cvt_w_kernel<<<dim3(DIM * DIM / (256 * 4), 4), 256, 0, stream>>>(
      Wq, Wk, Wv, Wo, Wq_b, Wk_b, Wv_b, Wo_b);

  ProjArgs pa;
  pa.A[0] = query; pa.A[1] = key_in; pa.A[2] = value;
  pa.W[0] = Wq_b;  pa.W[1] = Wk_b;   pa.W[2] = Wv_b;
  pa.bias[0] = bq; pa.bias[1] = bk;  pa.bias[2] = bv;
  pa.out[0] = Q_b; pa.out[1] = K_b;  pa.out[2] = Vt_b;
  proj_gemm<<<dim3(512, 1, 3), 256, 0, stream>>>(pa);

  attn_kernel<<<dim3(1024), 256, 0, stream>>>(Q_b, K_b, Vt_b, C_b);

  out_gemm<<<dim3(512), 256, 0, stream>>>(C_b, Wo_b, bo, (float*)d_out);
}